// Round 6
// baseline (535.956 us; speedup 1.0000x reference)
//
#include <hip/hip_runtime.h>

// GRU_27212912787836 : 2-layer GRU, B=512, T=1024, IN=3, H=64 (fp32 in/out)
// bf16 MFMA internally, fp32 cell math/state.
//
// Round 9: two-phase publication on top of round-8's merged-layer waves.
// 128 blocks x 256 thr (4 waves, 1/SIMD). Block owns 4 batches at MFMA
// M-rows {0,4,8,12}; wave jt owns feature tile jt for BOTH layers.
// Per round t: h0(t)=GRU0(h0(t-1),x(t)); h1(t-1)=GRU1(h1(t-2),h0(t-1)).
// NEW: h0 publishes at barrier A (mid-round), h1 at barrier B (end):
//   [L0-hh(6) | L1-ih(6) on a=h0(t-1)] ∥ cell-L0 -> write h0(t)
//   [L1-hh(6) on g=h1(t-2)] -> drain+barrier A -> issue read a_new=h0(t)
//   cell-L1 (a-read latency hides here) -> write h1(t-1) + out store
//   drain+barrier B -> issue read g_new=h1(t-1) (latency hides under the
//   next round's first 12 MFMAs, which don't touch g).
// So every ds_read's ~120cy latency is covered by independent work; the
// only exposed tail is cell-L1 + two bare 4-wave barriers. Global stores
// never drain in-loop (no vmcnt waits). WAR safe: reads are lgkm-drained
// one barrier before their buffer is rewritten (2x double-buffered).
// 8.4M SQ_LDS_BANK_CONFLICT = benign 2-lanes/bank minimum aliasing of
// wave64 b128 reads (2-way is free, m136) -- intentionally not chased.

typedef __attribute__((ext_vector_type(8))) short short8;   // 8 bf16
typedef __attribute__((ext_vector_type(4))) float floatx4;  // MFMA C/D

#define MFMA16(a, b, c) __builtin_amdgcn_mfma_f32_16x16x32_bf16((a), (b), (c), 0, 0, 0)

static constexpr int kB = 512;
static constexpr int kT = 1024;
static constexpr int kIN = 3;
static constexpr int kH = 64;
static constexpr int LDH = 72;  // padded LDS row stride (bf16); rows 16B-aligned
static constexpr float kL2E = 1.44269504f;

__device__ __forceinline__ unsigned short f2bf(float f) {
  unsigned u = __builtin_bit_cast(unsigned, f);
  return (unsigned short)((u + 0x7FFFu + ((u >> 16) & 1u)) >> 16);
}
__device__ __forceinline__ short8 cvt8s(const float* p, float s) {
  short8 f;
#pragma unroll
  for (int j = 0; j < 8; ++j) f[j] = (short)f2bf(p[j] * s);
  return f;
}
__device__ __forceinline__ float sig2(float a) {  // sigma of pre-scaled acc
  return __builtin_amdgcn_rcpf(1.0f + __builtin_amdgcn_exp2f(a));
}

// LDS-only drain + barrier: global ops stay in flight.
#define BLOCK_SYNC() asm volatile("s_waitcnt lgkmcnt(0)\n\ts_barrier" ::: "memory")

__global__ __launch_bounds__(256, 1) void gru_kernel(
    const float* __restrict__ x,
    const float* __restrict__ Wih0, const float* __restrict__ Whh0,
    const float* __restrict__ bih0, const float* __restrict__ bhh0,
    const float* __restrict__ Wih1, const float* __restrict__ Whh1,
    const float* __restrict__ bih1, const float* __restrict__ bhh1,
    float* __restrict__ out) {
  const int tid  = threadIdx.x;
  const int lane = tid & 63;
  const int jt   = tid >> 6;      // wave = feature tile 0..3
  const int c    = lane & 15;
  const int grp  = lane >> 4;     // batch index within block (M-row 4*grp)
  const int f    = jt * 16 + c;   // feature owned by this lane
  const int b    = blockIdx.x * 4 + grp;

  __shared__ __align__(16) unsigned short h0buf[2][16 * LDH];
  __shared__ __align__(16) unsigned short h1buf[2][16 * LDH];
  {  // zero once: A-rows != 0 mod 4 must read 0 forever; h1buf[0]=h1(-1)=0
    unsigned short* z0 = &h0buf[0][0];
    unsigned short* z1 = &h1buf[0][0];
    for (int i = tid; i < 2 * 16 * LDH; i += 256) { z0[i] = 0; z1[i] = 0; }
  }
  __syncthreads();  // once, outside the loop

  const float gsc[3] = {-kL2E, -kL2E, 2.0f * kL2E};
  const floatx4 Z = {0.f, 0.f, 0.f, 0.f};

  // ---- weights (B-fragments, pre-scaled bf16) ----
  short8 wh0[3][2], wi1[3][2], wh1[3][2];
  float wx[3][3];
#pragma unroll
  for (int g = 0; g < 3; ++g) {
    const int row = g * 64 + f;
#pragma unroll
    for (int k = 0; k < 2; ++k) {
      wh0[g][k] = cvt8s(Whh0 + row * kH + k * 32 + grp * 8, gsc[g]);
      wi1[g][k] = cvt8s(Wih1 + row * kH + k * 32 + grp * 8, gsc[g]);
      wh1[g][k] = cvt8s(Whh1 + row * kH + k * 32 + grp * 8, gsc[g]);
    }
#pragma unroll
    for (int i = 0; i < 3; ++i) wx[g][i] = Wih0[row * kIN + i] * gsc[g];
  }
  const float b0r  = gsc[0] * (bih0[f] + bhh0[f]);
  const float b0z  = gsc[1] * (bih0[64 + f] + bhh0[64 + f]);
  const float b0nx = gsc[2] * bih0[128 + f];
  const float b0nh = gsc[2] * bhh0[128 + f];
  const float b1r  = gsc[0] * (bih1[f] + bhh1[f]);
  const float b1z  = gsc[1] * (bih1[64 + f] + bhh1[64 + f]);
  const float b1nx = gsc[2] * bih1[128 + f];
  const float b1nh = gsc[2] * bhh1[128 + f];

  // ---- x pipeline (scalar fp32 gates, bias folded) ----
  const float* xb = x + (size_t)b * kT * kIN;
  float cx0 = xb[0], cx1 = xb[1], cx2 = xb[2];
  float gxr = fmaf(wx[0][0], cx0, fmaf(wx[0][1], cx1, fmaf(wx[0][2], cx2, b0r)));
  float gxz = fmaf(wx[1][0], cx0, fmaf(wx[1][1], cx1, fmaf(wx[1][2], cx2, b0z)));
  float gxn = fmaf(wx[2][0], cx0, fmaf(wx[2][1], cx1, fmaf(wx[2][2], cx2, b0nx)));
  float nx0 = xb[3], nx1 = xb[4], nx2 = xb[5];

  const int wadr = (4 * grp) * LDH + f;       // LDS write offset (shorts)
  const int ra0  = c * LDH + grp * 8;         // A-frag read offsets
  const int ra1  = ra0 + 32;
  float* ob = out + (size_t)b * kT * kH + f;
  const size_t FH = (size_t)kB * kT * kH;

  short8 a0 = {0, 0, 0, 0, 0, 0, 0, 0}, a1 = a0;  // h0(t-1) frags
  short8 g0 = a0, g1 = a0;                        // h1(t-2) frags
  float h0p = 0.f, h1p = 0.f;

  // ================= round 0: L0 only, same 2-barrier shape =================
  {
    floatx4 pr = MFMA16(a0, wh0[0][0], Z); pr = MFMA16(a1, wh0[0][1], pr);
    floatx4 pz = MFMA16(a0, wh0[1][0], Z); pz = MFMA16(a1, wh0[1][1], pz);
    floatx4 pn = MFMA16(a0, wh0[2][0], Z); pn = MFMA16(a1, wh0[2][1], pn);
    float r_ = sig2(pr[0] + gxr);
    float z_ = sig2(pz[0] + gxz);
    float u  = sig2(gxn + r_ * (pn[0] + b0nh));
    float ng = 1.0f - 2.0f * u;
    float hn = ng + z_ * (h0p - ng);
    h0p = hn;
    h0buf[0][wadr] = f2bf(hn);
    BLOCK_SYNC();  // barrier A(0): h0(0) published
    {
      const unsigned short* s0 = &h0buf[0][0];
      a0 = *(const short8*)(s0 + ra0); a1 = *(const short8*)(s0 + ra1);
    }
    gxr = fmaf(wx[0][0], nx0, fmaf(wx[0][1], nx1, fmaf(wx[0][2], nx2, b0r)));
    gxz = fmaf(wx[1][0], nx0, fmaf(wx[1][1], nx1, fmaf(wx[1][2], nx2, b0z)));
    gxn = fmaf(wx[2][0], nx0, fmaf(wx[2][1], nx1, fmaf(wx[2][2], nx2, b0nx)));
    nx0 = xb[6]; nx1 = xb[7]; nx2 = xb[8];
    BLOCK_SYNC();  // barrier B(0): h1(-1) (= zeros, pre-initialized)
    {
      const unsigned short* s1 = &h1buf[0][0];
      g0 = *(const short8*)(s1 + ra0); g1 = *(const short8*)(s1 + ra1);
    }
  }

  // ================= rounds 1..T-1 (branchless hot loop) =================
#pragma unroll 1
  for (int t = 1; t < kT; ++t) {
    // --- 12 MFMAs on a = h0(t-1): L0-hh then L1-ih (g not touched yet) ---
    floatx4 pr = MFMA16(a0, wh0[0][0], Z); pr = MFMA16(a1, wh0[0][1], pr);
    floatx4 pz = MFMA16(a0, wh0[1][0], Z); pz = MFMA16(a1, wh0[1][1], pz);
    floatx4 pn = MFMA16(a0, wh0[2][0], Z); pn = MFMA16(a1, wh0[2][1], pn);
    floatx4 qr = MFMA16(a0, wi1[0][0], Z); qr = MFMA16(a1, wi1[0][1], qr);
    floatx4 qz = MFMA16(a0, wi1[1][0], Z); qz = MFMA16(a1, wi1[1][1], qz);
    floatx4 qn = MFMA16(a0, wi1[2][0], Z); qn = MFMA16(a1, wi1[2][1], qn);

    // --- cell L0 (VALU; scheduler interleaves into MFMA pipe shadows) ---
    {
      float r_ = sig2(pr[0] + gxr);
      float z_ = sig2(pz[0] + gxz);
      float u  = sig2(gxn + r_ * (pn[0] + b0nh));
      float ng = 1.0f - 2.0f * u;
      float hn = ng + z_ * (h0p - ng);
      h0p = hn;
      h0buf[t & 1][wadr] = f2bf(hn);
    }

    // --- 6 MFMAs on g = h1(t-2): L1-hh (issued before barrier A) ---
    floatx4 sr = MFMA16(g0, wh1[0][0], Z); sr = MFMA16(g1, wh1[0][1], sr);
    floatx4 sz = MFMA16(g0, wh1[1][0], Z); sz = MFMA16(g1, wh1[1][1], sz);
    floatx4 sn = MFMA16(g0, wh1[2][0], Z); sn = MFMA16(g1, wh1[2][1], sn);

    BLOCK_SYNC();  // barrier A: h0(t) published by all waves

    // issue a_new reads NOW; latency hides under x-gates + cell-L1
    short8 a0n, a1n;
    {
      const unsigned short* s0 = &h0buf[t & 1][0];
      a0n = *(const short8*)(s0 + ra0); a1n = *(const short8*)(s0 + ra1);
    }

    // --- x gates for t+1 (garbage at t=T-1, never used) + prefetch t+2 ---
    gxr = fmaf(wx[0][0], nx0, fmaf(wx[0][1], nx1, fmaf(wx[0][2], nx2, b0r)));
    gxz = fmaf(wx[1][0], nx0, fmaf(wx[1][1], nx1, fmaf(wx[1][2], nx2, b0z)));
    gxn = fmaf(wx[2][0], nx0, fmaf(wx[2][1], nx1, fmaf(wx[2][2], nx2, b0nx)));
    {
      const int tp = (t + 2 < kT) ? t + 2 : kT - 1;  // clamped prefetch
      const float* p = xb + (size_t)tp * kIN;
      nx0 = p[0]; nx1 = p[1]; nx2 = p[2];
    }

    // --- cell L1 -> h1(t-1) ---
    {
      float r_ = sig2(qr[0] + sr[0] + b1r);
      float z_ = sig2(qz[0] + sz[0] + b1z);
      float u  = sig2(qn[0] + b1nx + r_ * (sn[0] + b1nh));
      float ng = 1.0f - 2.0f * u;
      float hn = ng + z_ * (h1p - ng);
      h1p = hn;
      h1buf[t & 1][wadr] = f2bf(hn);
      ob[(size_t)(t - 1) * kH] = hn;  // stays in flight; no vmcnt drain
    }

    BLOCK_SYNC();  // barrier B: h1(t-1) published by all waves

    // issue g_new reads; latency hides under next round's 12 a-MFMAs
    {
      const unsigned short* s1 = &h1buf[t & 1][0];
      g0 = *(const short8*)(s1 + ra0); g1 = *(const short8*)(s1 + ra1);
    }
    a0 = a0n; a1 = a1n;
  }

  // ================= round T: L1 only -> h1(T-1) =================
  {
    floatx4 qr = MFMA16(a0, wi1[0][0], Z); qr = MFMA16(a1, wi1[0][1], qr);
    floatx4 qz = MFMA16(a0, wi1[1][0], Z); qz = MFMA16(a1, wi1[1][1], qz);
    floatx4 qn = MFMA16(a0, wi1[2][0], Z); qn = MFMA16(a1, wi1[2][1], qn);
    floatx4 sr = MFMA16(g0, wh1[0][0], Z); sr = MFMA16(g1, wh1[0][1], sr);
    floatx4 sz = MFMA16(g0, wh1[1][0], Z); sz = MFMA16(g1, wh1[1][1], sz);
    floatx4 sn = MFMA16(g0, wh1[2][0], Z); sn = MFMA16(g1, wh1[2][1], sn);
    float r_ = sig2(qr[0] + sr[0] + b1r);
    float z_ = sig2(qz[0] + sz[0] + b1z);
    float u  = sig2(qn[0] + b1nx + r_ * (sn[0] + b1nh));
    float ng = 1.0f - 2.0f * u;
    float hn = ng + z_ * (h1p - ng);
    ob[(size_t)(kT - 1) * kH] = hn;
    out[FH + (size_t)b * kH + f] = hn;
  }
}

extern "C" void kernel_launch(void* const* d_in, const int* in_sizes, int n_in,
                              void* d_out, int out_size, void* d_ws, size_t ws_size,
                              hipStream_t stream) {
  const float* xp   = (const float*)d_in[0];
  const float* wih0 = (const float*)d_in[1];
  const float* whh0 = (const float*)d_in[2];
  const float* bih0 = (const float*)d_in[3];
  const float* bhh0 = (const float*)d_in[4];
  const float* wih1 = (const float*)d_in[5];
  const float* whh1 = (const float*)d_in[6];
  const float* bih1 = (const float*)d_in[7];
  const float* bhh1 = (const float*)d_in[8];
  float* outp = (float*)d_out;
  hipLaunchKernelGGL(gru_kernel, dim3(kB / 4), dim3(256), 0, stream,
                     xp, wih0, whh0, bih0, bhh0, wih1, whh1, bih1, bhh1, outp);
}